// Round 1
// baseline (1147.695 us; speedup 1.0000x reference)
//
#include <hip/hip_runtime.h>
#include <math.h>

#define NLEV 16
#define TBL (1u << 19)
#define TMASK (TBL - 1u)

struct LevelParams {
    float scale[NLEV];
    unsigned int res[NLEV];
    unsigned int dense_mask;  // bit l set => dense (stride) indexing
};

__global__ __launch_bounds__(256) void hashenc_kernel(
    const float* __restrict__ coords,
    const float* __restrict__ table,
    float* __restrict__ out,
    LevelParams lp, int npts)
{
    int gid = blockIdx.x * 256 + threadIdx.x;
    int n = gid >> 4;
    if (n >= npts) return;
    int l = gid & 15;

    float c0 = coords[3 * n + 0];
    float c1 = coords[3 * n + 1];
    float c2 = coords[3 * n + 2];

    float s = lp.scale[l];
    // match reference op order: coords01 = (c+1)/2; pos = coords01*scale + 0.5
    float p0 = ((c0 + 1.0f) * 0.5f) * s + 0.5f;
    float p1 = ((c1 + 1.0f) * 0.5f) * s + 0.5f;
    float p2 = ((c2 + 1.0f) * 0.5f) * s + 0.5f;
    float fp0 = floorf(p0), fp1 = floorf(p1), fp2 = floorf(p2);
    float f0 = p0 - fp0, f1 = p1 - fp1, f2 = p2 - fp2;
    unsigned int g0 = (unsigned int)fp0;
    unsigned int g1 = (unsigned int)fp1;
    unsigned int g2 = (unsigned int)fp2;

    const float* tl = table + (size_t)l * (size_t)TBL * 2u;
    const bool dense = (lp.dense_mask >> l) & 1u;
    const unsigned int res = lp.res[l];

    float acc0 = 0.0f, acc1 = 0.0f;
    #pragma unroll
    for (int c = 0; c < 8; ++c) {
        unsigned int b0 = (c >> 2) & 1u;  // dim 0 (stride 1 / prime 1)
        unsigned int b1 = (c >> 1) & 1u;  // dim 1 (stride res / prime 2654435761)
        unsigned int b2 = c & 1u;         // dim 2 (stride res^2 / prime 805459861)
        unsigned int x = g0 + b0;
        unsigned int y = g1 + b1;
        unsigned int z = g2 + b2;
        unsigned int idx;
        if (dense) {
            idx = (x + y * res + z * res * res) & TMASK;  // % 2^19 (T is pow2)
        } else {
            idx = (x ^ (y * 2654435761u) ^ (z * 805459861u)) & TMASK;
        }
        float w = (b0 ? f0 : 1.0f - f0) *
                  (b1 ? f1 : 1.0f - f1) *
                  (b2 ? f2 : 1.0f - f2);
        const float2 f = *reinterpret_cast<const float2*>(tl + (size_t)idx * 2u);
        acc0 += w * f.x;
        acc1 += w * f.y;
    }

    float2* op = reinterpret_cast<float2*>(out + (size_t)n * 32 + (size_t)l * 2);
    *op = make_float2(acc0, acc1);
}

extern "C" void kernel_launch(void* const* d_in, const int* in_sizes, int n_in,
                              void* d_out, int out_size, void* d_ws, size_t ws_size,
                              hipStream_t stream) {
    const float* coords = (const float*)d_in[0];
    const float* table  = (const float*)d_in[1];
    float* out = (float*)d_out;
    int npts = in_sizes[0] / 3;

    LevelParams lp;
    const double growth = exp((log(2048.0) - log(16.0)) / 15.0);
    unsigned int dm = 0;
    for (int l = 0; l < NLEV; ++l) {
        double sc = 16.0 * pow(growth, (double)l) - 1.0;  // matches MIN_RES*GROWTH**l - 1.0
        lp.scale[l] = (float)sc;                          // jnp.float32(scale)
        long long r = (long long)ceil(sc) + 1;            // int(math.ceil(scale)) + 1
        lp.res[l] = (unsigned int)r;
        if (r * r * r <= (long long)TBL) dm |= (1u << l); // res**3 <= T -> dense
    }
    lp.dense_mask = dm;

    int total = npts * NLEV;
    int blocks = (total + 255) / 256;
    hipLaunchKernelGGL(hashenc_kernel, dim3(blocks), dim3(256), 0, stream,
                       coords, table, out, lp, npts);
}

// Round 2
// 687.469 us; speedup vs baseline: 1.6695x; 1.6695x over previous
//
#include <hip/hip_runtime.h>
#include <math.h>

#define NLEV 16
#define TBL (1u << 19)
#define TMASK (TBL - 1u)

struct LevelParams {
    float scale[NLEV];
    unsigned int res[NLEV];
    unsigned int dense_mask;  // bit l set => dense (stride) indexing
};

__device__ __forceinline__ void encode_point_level(
    float c0, float c1, float c2, float s, unsigned int res, bool dense,
    const float* __restrict__ tl, float& acc0, float& acc1)
{
    // match reference op order: coords01 = (c+1)/2; pos = coords01*scale + 0.5
    float p0 = ((c0 + 1.0f) * 0.5f) * s + 0.5f;
    float p1 = ((c1 + 1.0f) * 0.5f) * s + 0.5f;
    float p2 = ((c2 + 1.0f) * 0.5f) * s + 0.5f;
    float fp0 = floorf(p0), fp1 = floorf(p1), fp2 = floorf(p2);
    float f0 = p0 - fp0, f1 = p1 - fp1, f2 = p2 - fp2;
    unsigned int g0 = (unsigned int)fp0;
    unsigned int g1 = (unsigned int)fp1;
    unsigned int g2 = (unsigned int)fp2;

    acc0 = 0.0f; acc1 = 0.0f;
    #pragma unroll
    for (int c = 0; c < 8; ++c) {
        unsigned int b0 = (c >> 2) & 1u;
        unsigned int b1 = (c >> 1) & 1u;
        unsigned int b2 = c & 1u;
        unsigned int x = g0 + b0;
        unsigned int y = g1 + b1;
        unsigned int z = g2 + b2;
        unsigned int idx;
        if (dense) {
            idx = (x + y * res + z * res * res) & TMASK;
        } else {
            idx = (x ^ (y * 2654435761u) ^ (z * 805459861u)) & TMASK;
        }
        float w = (b0 ? f0 : 1.0f - f0) *
                  (b1 ? f1 : 1.0f - f1) *
                  (b2 ? f2 : 1.0f - f2);
        const float2 f = *reinterpret_cast<const float2*>(tl + (size_t)idx * 2u);
        acc0 += w * f.x;
        acc1 += w * f.y;
    }
}

// Level-major: blockIdx = l * blocksPerLevel + chunk. At any instant the
// dispatch window covers ~1-2 levels -> each XCD's 4 MB L2 holds the active
// level's 4 MB table -> gathers become L2 hits instead of HBM fetches.
__global__ __launch_bounds__(256) void hashenc_level_kernel(
    const float* __restrict__ coords,
    const float* __restrict__ table,
    float* __restrict__ ws,           // [L][N][2] contiguous per level
    LevelParams lp, int npts, int blocksPerLevel)
{
    int l = blockIdx.x / blocksPerLevel;
    int n = (blockIdx.x - l * blocksPerLevel) * 256 + threadIdx.x;
    if (n >= npts) return;

    float c0 = coords[3 * n + 0];
    float c1 = coords[3 * n + 1];
    float c2 = coords[3 * n + 2];

    const float* tl = table + (size_t)l * (size_t)TBL * 2u;
    float acc0, acc1;
    encode_point_level(c0, c1, c2, lp.scale[l], lp.res[l],
                       (lp.dense_mask >> l) & 1u, tl, acc0, acc1);

    float2* op = reinterpret_cast<float2*>(ws) + (size_t)l * npts + n;
    *op = make_float2(acc0, acc1);
}

// [L][N][2] -> [N][L*2]; reads coalesced per level, writes 128 B per point.
__global__ __launch_bounds__(256) void transpose_kernel(
    const float* __restrict__ ws, float* __restrict__ out, int npts)
{
    int n = blockIdx.x * 256 + threadIdx.x;
    if (n >= npts) return;
    float buf[32];
    const float2* wsp = reinterpret_cast<const float2*>(ws);
    #pragma unroll
    for (int l = 0; l < NLEV; ++l) {
        float2 f = wsp[(size_t)l * npts + n];
        buf[2 * l] = f.x;
        buf[2 * l + 1] = f.y;
    }
    float4* op = reinterpret_cast<float4*>(out + (size_t)n * 32);
    #pragma unroll
    for (int i = 0; i < 8; ++i) {
        op[i] = make_float4(buf[4 * i], buf[4 * i + 1], buf[4 * i + 2], buf[4 * i + 3]);
    }
}

// Fallback (round-1 kernel): point-major, direct out writes.
__global__ __launch_bounds__(256) void hashenc_kernel(
    const float* __restrict__ coords,
    const float* __restrict__ table,
    float* __restrict__ out,
    LevelParams lp, int npts)
{
    int gid = blockIdx.x * 256 + threadIdx.x;
    int n = gid >> 4;
    if (n >= npts) return;
    int l = gid & 15;
    float c0 = coords[3 * n + 0];
    float c1 = coords[3 * n + 1];
    float c2 = coords[3 * n + 2];
    const float* tl = table + (size_t)l * (size_t)TBL * 2u;
    float acc0, acc1;
    encode_point_level(c0, c1, c2, lp.scale[l], lp.res[l],
                       (lp.dense_mask >> l) & 1u, tl, acc0, acc1);
    float2* op = reinterpret_cast<float2*>(out + (size_t)n * 32 + (size_t)l * 2);
    *op = make_float2(acc0, acc1);
}

extern "C" void kernel_launch(void* const* d_in, const int* in_sizes, int n_in,
                              void* d_out, int out_size, void* d_ws, size_t ws_size,
                              hipStream_t stream) {
    const float* coords = (const float*)d_in[0];
    const float* table  = (const float*)d_in[1];
    float* out = (float*)d_out;
    int npts = in_sizes[0] / 3;

    LevelParams lp;
    const double growth = exp((log(2048.0) - log(16.0)) / 15.0);
    unsigned int dm = 0;
    for (int l = 0; l < NLEV; ++l) {
        double sc = 16.0 * pow(growth, (double)l) - 1.0;
        lp.scale[l] = (float)sc;
        long long r = (long long)ceil(sc) + 1;
        lp.res[l] = (unsigned int)r;
        if (r * r * r <= (long long)TBL) dm |= (1u << l);
    }
    lp.dense_mask = dm;

    size_t ws_needed = (size_t)npts * NLEV * 2 * sizeof(float);
    if (ws_size >= ws_needed) {
        int blocksPerLevel = (npts + 255) / 256;
        hipLaunchKernelGGL(hashenc_level_kernel,
                           dim3(blocksPerLevel * NLEV), dim3(256), 0, stream,
                           coords, table, (float*)d_ws, lp, npts, blocksPerLevel);
        hipLaunchKernelGGL(transpose_kernel,
                           dim3(blocksPerLevel), dim3(256), 0, stream,
                           (const float*)d_ws, out, npts);
    } else {
        int total = npts * NLEV;
        int blocks = (total + 255) / 256;
        hipLaunchKernelGGL(hashenc_kernel, dim3(blocks), dim3(256), 0, stream,
                           coords, table, out, lp, npts);
    }
}